// Round 15
// baseline (1431.686 us; speedup 1.0000x reference)
//
#include <hip/hip_runtime.h>
#include <cstdint>
#include <cstddef>

#define NN 8192
#define INF 512
#define OUTF 64
#define ALPHA 0.2f
#define NSPLIT 16
#define JSPLIT (NN / NSPLIT)     // 512
#define NW32 (NN / 32)           // 256
#define GEMM_BLOCKS 512
// fused-probe geometry
#define NSPLIT_F 8
#define JSPLIT_F (NN / NSPLIT_F) // 1024

typedef short bf16x8 __attribute__((ext_vector_type(8)));
typedef float f32x4 __attribute__((ext_vector_type(4)));

static __device__ inline unsigned short f2bf(float f) {
    unsigned u = __builtin_bit_cast(unsigned, f);
    unsigned r = (u + 0x7FFFu + ((u >> 16) & 1u)) >> 16;
    return (unsigned short)r;
}

// ===========================================================================
// REAL PIPELINE (round-11 best config, 91.5 us) — unchanged.
// ===========================================================================
__global__ __launch_bounds__(256) void k01_fused(
    const float* __restrict__ x, const int* __restrict__ adj,
    const float* __restrict__ W, const float* __restrict__ a,
    unsigned short* __restrict__ Asw, float* __restrict__ U,
    float* __restrict__ E2p, float* __restrict__ E2n,
    unsigned* __restrict__ mask)
{
    __shared__ int ldsbuf[8192];
    const int tid = threadIdx.x;

    if (blockIdx.x >= GEMM_BLOCKS) {
        const int row = blockIdx.x - GEMM_BLOCKS;
        const int* arow = adj + (size_t)row * NN;
        #pragma unroll
        for (int k = 0; k < 8; ++k) {
            const int i = k * 1024 + tid * 4;
            int4 v = *(const int4*)(arow + i);
            const int p = i ^ (((i >> 7) & 7) << 2);
            *(int4*)&ldsbuf[p] = v;
        }
        __syncthreads();
        unsigned m = 0;
        #pragma unroll
        for (int k = 0; k < 8; ++k) {
            const int i2 = tid * 32 + k * 4;
            const int p2 = i2 ^ (((i2 >> 7) & 7) << 2);
            int4 v = *(const int4*)&ldsbuf[p2];
            m |= (v.x != 0 ? 1u : 0u) << (4 * k);
            m |= (v.y != 0 ? 1u : 0u) << (4 * k + 1);
            m |= (v.z != 0 ? 1u : 0u) << (4 * k + 2);
            m |= (v.w != 0 ? 1u : 0u) << (4 * k + 3);
        }
        mask[(size_t)row * NW32 + tid] = m;
        return;
    }

    const int i0 = blockIdx.x * 16;
    const int w  = __builtin_amdgcn_readfirstlane(tid >> 6);
    const int c  = tid & 63;
    const float* xr = x + (size_t)(i0 + 4 * w) * INF;
    const float* Wc = W + c;
    float acc[4] = {0.f, 0.f, 0.f, 0.f};

    #pragma unroll 4
    for (int kk = 0; kk < 128; ++kk) {
        const float4 x0 = *(const float4*)(xr + 0 * INF + kk * 4);
        const float4 x1 = *(const float4*)(xr + 1 * INF + kk * 4);
        const float4 x2 = *(const float4*)(xr + 2 * INF + kk * 4);
        const float4 x3 = *(const float4*)(xr + 3 * INF + kk * 4);
        const float w0 = Wc[(kk * 4 + 0) * OUTF];
        const float w1 = Wc[(kk * 4 + 1) * OUTF];
        const float w2 = Wc[(kk * 4 + 2) * OUTF];
        const float w3 = Wc[(kk * 4 + 3) * OUTF];
        acc[0] = fmaf(x0.x, w0, fmaf(x0.y, w1, fmaf(x0.z, w2, fmaf(x0.w, w3, acc[0]))));
        acc[1] = fmaf(x1.x, w0, fmaf(x1.y, w1, fmaf(x1.z, w2, fmaf(x1.w, w3, acc[1]))));
        acc[2] = fmaf(x2.x, w0, fmaf(x2.y, w1, fmaf(x2.z, w2, fmaf(x2.w, w3, acc[2]))));
        acc[3] = fmaf(x3.x, w0, fmaf(x3.y, w1, fmaf(x3.z, w2, fmaf(x3.w, w3, acc[3]))));
    }

    const float a1c = a[c];
    const float a2c = a[64 + c];
    #pragma unroll
    for (int q = 0; q < 4; ++q) {
        float v1 = acc[q] * a1c;
        float v2 = acc[q] * a2c;
        #pragma unroll
        for (int m = 32; m; m >>= 1) {
            v1 += __shfl_xor(v1, m, 64);
            v2 += __shfl_xor(v2, m, 64);
        }
        if (c == 0) {
            const int i = i0 + 4 * w + q;
            U[i]   = __expf((1.0f - ALPHA) * v1);
            E2p[i] = __expf(v2);
            E2n[i] = __expf(ALPHA * v2);
        }
    }

    const int i   = i0 + 4 * w;
    const int jt  = i >> 5;
    const int sub = (i >> 3) & 3;
    const int e0  = i & 7;
    ushort4 pk;
    pk.x = f2bf(acc[0]); pk.y = f2bf(acc[1]);
    pk.z = f2bf(acc[2]); pk.w = f2bf(acc[3]);
    *(ushort4*)&Asw[((size_t)(c >> 4) * 256 + jt) * 512 + ((c & 15) + 16 * sub) * 8 + e0] = pk;
}

// round-11 k2 body, reusable by the probe (task passed in).
__device__ __forceinline__ void k2_body(
    const unsigned* __restrict__ mask, const unsigned short* __restrict__ Asw,
    const float* __restrict__ Ug, const float* __restrict__ E2pg,
    const float* __restrict__ E2ng,
    float* __restrict__ Opart, float* __restrict__ lpart, int l, int task)
{
    const int it    = task >> 4;
    const int split = task & 15;
    const int i0    = it * 32;
    const int jbase = split * JSPLIT;
    const int jb32  = jbase >> 5;

    const int il  = l & 15;
    const int kg  = l >> 4;
    const int kg8 = kg * 8;

    const float ua = Ug[i0 + il];
    const float ub = Ug[i0 + 16 + il];

    const unsigned* mbase = mask + (size_t)(i0 + il) * NW32 + jb32 + kg;
    unsigned mA[4], mB[4];
    #pragma unroll
    for (int ss = 0; ss < 4; ++ss) {
        mA[ss] = mbase[ss * 4];
        mB[ss] = mbase[(size_t)16 * NW32 + ss * 4];
    }

    f32x4 a00 = {0,0,0,0}, a01 = {0,0,0,0}, a10 = {0,0,0,0}, a11 = {0,0,0,0};
    f32x4 a20 = {0,0,0,0}, a21 = {0,0,0,0}, a30 = {0,0,0,0}, a31 = {0,0,0,0};
    float rsA = 0.f, rsB = 0.f;

    float4 pc0 = *(const float4*)(E2pg + jbase + kg8);
    float4 pc1 = *(const float4*)(E2pg + jbase + kg8 + 4);
    float4 nc0 = *(const float4*)(E2ng + jbase + kg8);
    float4 nc1 = *(const float4*)(E2ng + jbase + kg8 + 4);
    unsigned bAc = (__shfl(mA[0], il, 64) >> kg8) & 0xffu;
    unsigned bBc = (__shfl(mB[0], il, 64) >> kg8) & 0xffu;

#define SCM(UU, EP, EN, BITS, K)                                              \
    ((((BITS) >> (K)) & 1u) ? fmaxf((UU) * (EP), (EN)) : 0.f)

    #pragma unroll
    for (int t = 0; t < 16; ++t) {
        const unsigned short* Ac = Asw + (size_t)(jb32 + t) * 512 + l * 8;
        bf16x8 A0c = *(const bf16x8*)(Ac);
        bf16x8 A1c = *(const bf16x8*)(Ac + 131072);
        bf16x8 A2c = *(const bf16x8*)(Ac + 262144);
        bf16x8 A3c = *(const bf16x8*)(Ac + 393216);

        const int tn = (t < 15) ? t + 1 : t;
        const float* epn = E2pg + jbase + tn * 32 + kg8;
        const float* enn = E2ng + jbase + tn * 32 + kg8;
        float4 pn0 = *(const float4*)(epn);
        float4 pn1 = *(const float4*)(epn + 4);
        float4 nn0 = *(const float4*)(enn);
        float4 nn1 = *(const float4*)(enn + 4);
        const int ssn = tn >> 2, ksn = tn & 3;
        unsigned bAn = (__shfl(mA[ssn], il + 16 * ksn, 64) >> kg8) & 0xffu;
        unsigned bBn = (__shfl(mB[ssn], il + 16 * ksn, 64) >> kg8) & 0xffu;

        const float p0 = SCM(ua, pc0.x, nc0.x, bAc, 0);
        const float p1 = SCM(ua, pc0.y, nc0.y, bAc, 1);
        const float p2 = SCM(ua, pc0.z, nc0.z, bAc, 2);
        const float p3 = SCM(ua, pc0.w, nc0.w, bAc, 3);
        const float p4 = SCM(ua, pc1.x, nc1.x, bAc, 4);
        const float p5 = SCM(ua, pc1.y, nc1.y, bAc, 5);
        const float p6 = SCM(ua, pc1.z, nc1.z, bAc, 6);
        const float p7 = SCM(ua, pc1.w, nc1.w, bAc, 7);
        const float q0 = SCM(ub, pc0.x, nc0.x, bBc, 0);
        const float q1 = SCM(ub, pc0.y, nc0.y, bBc, 1);
        const float q2 = SCM(ub, pc0.z, nc0.z, bBc, 2);
        const float q3 = SCM(ub, pc0.w, nc0.w, bBc, 3);
        const float q4 = SCM(ub, pc1.x, nc1.x, bBc, 4);
        const float q5 = SCM(ub, pc1.y, nc1.y, bBc, 5);
        const float q6 = SCM(ub, pc1.z, nc1.z, bBc, 6);
        const float q7 = SCM(ub, pc1.w, nc1.w, bBc, 7);

        rsA += ((p0 + p1) + (p2 + p3)) + ((p4 + p5) + (p6 + p7));
        rsB += ((q0 + q1) + (q2 + q3)) + ((q4 + q5) + (q6 + q7));

        uint4 wa, wb;
        asm("v_cvt_pk_bf16_f32 %0, %1, %2" : "=v"(wa.x) : "v"(p0), "v"(p1));
        asm("v_cvt_pk_bf16_f32 %0, %1, %2" : "=v"(wa.y) : "v"(p2), "v"(p3));
        asm("v_cvt_pk_bf16_f32 %0, %1, %2" : "=v"(wa.z) : "v"(p4), "v"(p5));
        asm("v_cvt_pk_bf16_f32 %0, %1, %2" : "=v"(wa.w) : "v"(p6), "v"(p7));
        asm("v_cvt_pk_bf16_f32 %0, %1, %2" : "=v"(wb.x) : "v"(q0), "v"(q1));
        asm("v_cvt_pk_bf16_f32 %0, %1, %2" : "=v"(wb.y) : "v"(q2), "v"(q3));
        asm("v_cvt_pk_bf16_f32 %0, %1, %2" : "=v"(wb.z) : "v"(q4), "v"(q5));
        asm("v_cvt_pk_bf16_f32 %0, %1, %2" : "=v"(wb.w) : "v"(q6), "v"(q7));
        const bf16x8 BA = __builtin_bit_cast(bf16x8, wa);
        const bf16x8 BB = __builtin_bit_cast(bf16x8, wb);

        a00 = __builtin_amdgcn_mfma_f32_16x16x32_bf16(A0c, BA, a00, 0, 0, 0);
        a01 = __builtin_amdgcn_mfma_f32_16x16x32_bf16(A0c, BB, a01, 0, 0, 0);
        a10 = __builtin_amdgcn_mfma_f32_16x16x32_bf16(A1c, BA, a10, 0, 0, 0);
        a11 = __builtin_amdgcn_mfma_f32_16x16x32_bf16(A1c, BB, a11, 0, 0, 0);
        a20 = __builtin_amdgcn_mfma_f32_16x16x32_bf16(A2c, BA, a20, 0, 0, 0);
        a21 = __builtin_amdgcn_mfma_f32_16x16x32_bf16(A2c, BB, a21, 0, 0, 0);
        a30 = __builtin_amdgcn_mfma_f32_16x16x32_bf16(A3c, BA, a30, 0, 0, 0);
        a31 = __builtin_amdgcn_mfma_f32_16x16x32_bf16(A3c, BB, a31, 0, 0, 0);

        pc0 = pn0; pc1 = pn1; nc0 = nn0; nc1 = nn1;
        bAc = bAn; bBc = bBn;
    }
#undef SCM

    rsA += __shfl_xor(rsA, 16, 64);
    rsA += __shfl_xor(rsA, 32, 64);
    rsB += __shfl_xor(rsB, 16, 64);
    rsB += __shfl_xor(rsB, 32, 64);
    if (l < 16) {
        lpart[(size_t)split * NN + i0 + il]      = rsA;
        lpart[(size_t)split * NN + i0 + 16 + il] = rsB;
    }

    const int nn4 = kg * 4;
    float* OA = Opart + ((size_t)split * NN + i0 + il) * OUTF + nn4;
    float* OB = OA + (size_t)16 * OUTF;
    *(float4*)(OA)      = *(float4*)&a00;
    *(float4*)(OA + 16) = *(float4*)&a10;
    *(float4*)(OA + 32) = *(float4*)&a20;
    *(float4*)(OA + 48) = *(float4*)&a30;
    *(float4*)(OB)      = *(float4*)&a01;
    *(float4*)(OB + 16) = *(float4*)&a11;
    *(float4*)(OB + 32) = *(float4*)&a21;
    *(float4*)(OB + 48) = *(float4*)&a31;
}

__global__ __launch_bounds__(256, 4) void k2_attn(
    const unsigned* __restrict__ mask, const unsigned short* __restrict__ Asw,
    const float* __restrict__ Ug, const float* __restrict__ E2pg,
    const float* __restrict__ E2ng,
    float* __restrict__ Opart, float* __restrict__ lpart)
{
    k2_body(mask, Asw, Ug, E2pg, E2ng, Opart, lpart,
            threadIdx.x & 63, blockIdx.x * 4 + (threadIdx.x >> 6));
}

__global__ __launch_bounds__(256) void k3_combine(
    const float* __restrict__ Opart, const float* __restrict__ lpart,
    float* __restrict__ out)
{
    const int f4 = blockIdx.x * 256 + threadIdx.x;
    const int i  = f4 >> 4;
    float4 r = {0.f, 0.f, 0.f, 0.f};
    float  lsum = 0.f;
    #pragma unroll
    for (int s = 0; s < NSPLIT; ++s) {
        float4 o = *(const float4*)&Opart[(size_t)s * NN * OUTF + (size_t)f4 * 4];
        r.x += o.x; r.y += o.y; r.z += o.z; r.w += o.w;
        lsum += lpart[(size_t)s * NN + i];
    }
    float inv = 1.0f / lsum;
    r.x *= inv; r.y *= inv; r.z *= inv; r.w *= inv;
    *(float4*)&out[(size_t)f4 * 4] = r;
}

// ===========================================================================
// PROBES (scratch outputs, after real pipeline; rotate work per rep to defeat
// hoisting and stay in the L3-warm regime the timed replays run in).
// ===========================================================================

// mask-pack path x8 reps, rotated rows.
__global__ __launch_bounds__(256) void probe_maskpack(
    const int* __restrict__ adj, unsigned* __restrict__ mask2)
{
    __shared__ int ldsbuf[8192];
    const int tid = threadIdx.x;
    for (int rep = 0; rep < 8; ++rep) {
        const int row = (blockIdx.x + rep * 1024) & (NN - 1);
        const int* arow = adj + (size_t)row * NN;
        __syncthreads();
        #pragma unroll
        for (int k = 0; k < 8; ++k) {
            const int i = k * 1024 + tid * 4;
            int4 v = *(const int4*)(arow + i);
            const int p = i ^ (((i >> 7) & 7) << 2);
            *(int4*)&ldsbuf[p] = v;
        }
        __syncthreads();
        unsigned m = 0;
        #pragma unroll
        for (int k = 0; k < 8; ++k) {
            const int i2 = tid * 32 + k * 4;
            const int p2 = i2 ^ (((i2 >> 7) & 7) << 2);
            int4 v = *(const int4*)&ldsbuf[p2];
            m |= (v.x != 0 ? 1u : 0u) << (4 * k);
            m |= (v.y != 0 ? 1u : 0u) << (4 * k + 1);
            m |= (v.z != 0 ? 1u : 0u) << (4 * k + 2);
            m |= (v.w != 0 ? 1u : 0u) << (4 * k + 3);
        }
        mask2[(size_t)row * NW32 + tid] = m;
    }
}

// GEMM path x24 reps, rotated i-tiles.
__global__ __launch_bounds__(256) void probe_gemm(
    const float* __restrict__ x, const float* __restrict__ W,
    const float* __restrict__ a, unsigned short* __restrict__ Asw2,
    float* __restrict__ U2, float* __restrict__ E2p2, float* __restrict__ E2n2)
{
    const int tid = threadIdx.x;
    const int w   = __builtin_amdgcn_readfirstlane(tid >> 6);
    const int c   = tid & 63;
    for (int rep = 0; rep < 24; ++rep) {
        const int i0 = ((blockIdx.x + rep * 128) & 511) * 16;
        const float* xr = x + (size_t)(i0 + 4 * w) * INF;
        const float* Wc = W + c;
        float acc[4] = {0.f, 0.f, 0.f, 0.f};
        #pragma unroll 4
        for (int kk = 0; kk < 128; ++kk) {
            const float4 x0 = *(const float4*)(xr + 0 * INF + kk * 4);
            const float4 x1 = *(const float4*)(xr + 1 * INF + kk * 4);
            const float4 x2 = *(const float4*)(xr + 2 * INF + kk * 4);
            const float4 x3 = *(const float4*)(xr + 3 * INF + kk * 4);
            const float w0 = Wc[(kk * 4 + 0) * OUTF];
            const float w1 = Wc[(kk * 4 + 1) * OUTF];
            const float w2 = Wc[(kk * 4 + 2) * OUTF];
            const float w3 = Wc[(kk * 4 + 3) * OUTF];
            acc[0] = fmaf(x0.x, w0, fmaf(x0.y, w1, fmaf(x0.z, w2, fmaf(x0.w, w3, acc[0]))));
            acc[1] = fmaf(x1.x, w0, fmaf(x1.y, w1, fmaf(x1.z, w2, fmaf(x1.w, w3, acc[1]))));
            acc[2] = fmaf(x2.x, w0, fmaf(x2.y, w1, fmaf(x2.z, w2, fmaf(x2.w, w3, acc[2]))));
            acc[3] = fmaf(x3.x, w0, fmaf(x3.y, w1, fmaf(x3.z, w2, fmaf(x3.w, w3, acc[3]))));
        }
        const float a1c = a[c];
        const float a2c = a[64 + c];
        #pragma unroll
        for (int q = 0; q < 4; ++q) {
            float v1 = acc[q] * a1c;
            float v2 = acc[q] * a2c;
            #pragma unroll
            for (int m = 32; m; m >>= 1) {
                v1 += __shfl_xor(v1, m, 64);
                v2 += __shfl_xor(v2, m, 64);
            }
            if (c == 0) {
                const int i = i0 + 4 * w + q;
                U2[i]   = __expf((1.0f - ALPHA) * v1);
                E2p2[i] = __expf(v2);
                E2n2[i] = __expf(ALPHA * v2);
            }
        }
        const int i   = i0 + 4 * w;
        const int jt  = i >> 5;
        const int sub = (i >> 3) & 3;
        const int e0  = i & 7;
        ushort4 pk;
        pk.x = f2bf(acc[0]); pk.y = f2bf(acc[1]);
        pk.z = f2bf(acc[2]); pk.w = f2bf(acc[3]);
        *(ushort4*)&Asw2[((size_t)(c >> 4) * 256 + jt) * 512 + ((c & 15) + 16 * sub) * 8 + e0] = pk;
    }
}

// round-11 k2 x6 reps, rotated tasks.
__global__ __launch_bounds__(256, 4) void probe_k2attn(
    const unsigned* __restrict__ mask, const unsigned short* __restrict__ Asw,
    const float* __restrict__ Ug, const float* __restrict__ E2pg,
    const float* __restrict__ E2ng,
    float* __restrict__ Opart2, float* __restrict__ lpart2)
{
    const int l = threadIdx.x & 63;
    for (int rep = 0; rep < 6; ++rep) {
        const int task = (blockIdx.x * 4 + (threadIdx.x >> 6) + rep * 1024) & 4095;
        k2_body(mask, Asw, Ug, E2pg, E2ng, Opart2, lpart2, l, task);
    }
}

// round-14 fused kernel x4 reps, rotated blocks.
__global__ __launch_bounds__(256, 4) void probe_k2fused(
    const int* __restrict__ adj, const unsigned short* __restrict__ Asw,
    const float* __restrict__ Ug, const float* __restrict__ E2pg,
    const float* __restrict__ E2ng,
    float* __restrict__ Opart3, float* __restrict__ lpart3)
{
    __shared__ char smem[33280];
    unsigned (*lm)[34] = (unsigned(*)[34])smem;
    float* red  = (float*)smem;
    float* redl = (float*)(smem + 32768);

    const int tid = threadIdx.x;
    const int l   = tid & 63;
    const int w   = tid >> 6;

    for (int rep = 0; rep < 4; ++rep) {
        const int vb    = (blockIdx.x + rep * 512) & 2047;
        const int split = vb & (NSPLIT_F - 1);
        const int i0    = (vb >> 3) * 32;
        const int jbase = split * JSPLIT_F;
        const int jb32  = jbase >> 5;

        __syncthreads();   // previous rep fully done with LDS
        {
            const int* arow0 = adj + (size_t)i0 * NN + jbase;
            int vals[16];
            for (int batch = 0; batch < 8; ++batch) {
                #pragma unroll
                for (int u = 0; u < 16; ++u) {
                    const int r2 = batch * 16 + u;
                    vals[u] = arow0[(size_t)(r2 >> 2) * NN + (r2 & 3) * 256 + tid];
                }
                #pragma unroll
                for (int u = 0; u < 16; ++u) {
                    const int r2 = batch * 16 + u;
                    const unsigned long long b = __ballot(vals[u] != 0);
                    if ((tid & 63) == 0) {
                        *(unsigned long long*)&lm[r2 >> 2][(r2 & 3) * 8 + w * 2] = b;
                    }
                }
            }
        }
        __syncthreads();

        const int il  = l & 15;
        const int kg8 = (l >> 4) * 8;
        const float ua = Ug[i0 + il];
        const float ub = Ug[i0 + 16 + il];

        f32x4 a00 = {0,0,0,0}, a01 = {0,0,0,0}, a10 = {0,0,0,0}, a11 = {0,0,0,0};
        f32x4 a20 = {0,0,0,0}, a21 = {0,0,0,0}, a30 = {0,0,0,0}, a31 = {0,0,0,0};
        float rsA = 0.f, rsB = 0.f;

        int t = w;
        float4 pc0 = *(const float4*)(E2pg + jbase + t * 32 + kg8);
        float4 pc1 = *(const float4*)(E2pg + jbase + t * 32 + kg8 + 4);
        float4 nc0 = *(const float4*)(E2ng + jbase + t * 32 + kg8);
        float4 nc1 = *(const float4*)(E2ng + jbase + t * 32 + kg8 + 4);
        unsigned bAc = (lm[il][t]      >> kg8) & 0xffu;
        unsigned bBc = (lm[il + 16][t] >> kg8) & 0xffu;

#define SCM(UU, EP, EN, BITS, K)                                              \
    ((((BITS) >> (K)) & 1u) ? fmaxf((UU) * (EP), (EN)) : 0.f)
        #pragma unroll
        for (int s = 0; s < 8; ++s) {
            const unsigned short* Ap = Asw + (size_t)(jb32 + t) * 512 + l * 8;
            const bf16x8 A0 = *(const bf16x8*)(Ap);
            const bf16x8 A1 = *(const bf16x8*)(Ap + 131072);
            const bf16x8 A2 = *(const bf16x8*)(Ap + 262144);
            const bf16x8 A3 = *(const bf16x8*)(Ap + 393216);

            const int tn = (s < 7) ? t + 4 : t;
            float4 pn0 = *(const float4*)(E2pg + jbase + tn * 32 + kg8);
            float4 pn1 = *(const float4*)(E2pg + jbase + tn * 32 + kg8 + 4);
            float4 nn0 = *(const float4*)(E2ng + jbase + tn * 32 + kg8);
            float4 nn1 = *(const float4*)(E2ng + jbase + tn * 32 + kg8 + 4);
            unsigned bAn = (lm[il][tn]      >> kg8) & 0xffu;
            unsigned bBn = (lm[il + 16][tn] >> kg8) & 0xffu;

            const float p0 = SCM(ua, pc0.x, nc0.x, bAc, 0);
            const float p1 = SCM(ua, pc0.y, nc0.y, bAc, 1);
            const float p2 = SCM(ua, pc0.z, nc0.z, bAc, 2);
            const float p3 = SCM(ua, pc0.w, nc0.w, bAc, 3);
            const float p4 = SCM(ua, pc1.x, nc1.x, bAc, 4);
            const float p5 = SCM(ua, pc1.y, nc1.y, bAc, 5);
            const float p6 = SCM(ua, pc1.z, nc1.z, bAc, 6);
            const float p7 = SCM(ua, pc1.w, nc1.w, bAc, 7);
            const float q0 = SCM(ub, pc0.x, nc0.x, bBc, 0);
            const float q1 = SCM(ub, pc0.y, nc0.y, bBc, 1);
            const float q2 = SCM(ub, pc0.z, nc0.z, bBc, 2);
            const float q3 = SCM(ub, pc0.w, nc0.w, bBc, 3);
            const float q4 = SCM(ub, pc1.x, nc1.x, bBc, 4);
            const float q5 = SCM(ub, pc1.y, nc1.y, bBc, 5);
            const float q6 = SCM(ub, pc1.z, nc1.z, bBc, 6);
            const float q7 = SCM(ub, pc1.w, nc1.w, bBc, 7);

            rsA += ((p0 + p1) + (p2 + p3)) + ((p4 + p5) + (p6 + p7));
            rsB += ((q0 + q1) + (q2 + q3)) + ((q4 + q5) + (q6 + q7));

            uint4 wa, wb;
            asm("v_cvt_pk_bf16_f32 %0, %1, %2" : "=v"(wa.x) : "v"(p0), "v"(p1));
            asm("v_cvt_pk_bf16_f32 %0, %1, %2" : "=v"(wa.y) : "v"(p2), "v"(p3));
            asm("v_cvt_pk_bf16_f32 %0, %1, %2" : "=v"(wa.z) : "v"(p4), "v"(p5));
            asm("v_cvt_pk_bf16_f32 %0, %1, %2" : "=v"(wa.w) : "v"(p6), "v"(p7));
            asm("v_cvt_pk_bf16_f32 %0, %1, %2" : "=v"(wb.x) : "v"(q0), "v"(q1));
            asm("v_cvt_pk_bf16_f32 %0, %1, %2" : "=v"(wb.y) : "v"(q2), "v"(q3));
            asm("v_cvt_pk_bf16_f32 %0, %1, %2" : "=v"(wb.z) : "v"(q4), "v"(q5));
            asm("v_cvt_pk_bf16_f32 %0, %1, %2" : "=v"(wb.w) : "v"(q6), "v"(q7));
            const bf16x8 BA = __builtin_bit_cast(bf16x8, wa);
            const bf16x8 BB = __builtin_bit_cast(bf16x8, wb);

            a00 = __builtin_amdgcn_mfma_f32_16x16x32_bf16(A0, BA, a00, 0, 0, 0);
            a01 = __builtin_amdgcn_mfma_f32_16x16x32_bf16(A0, BB, a01, 0, 0, 0);
            a10 = __builtin_amdgcn_mfma_f32_16x16x32_bf16(A1, BA, a10, 0, 0, 0);
            a11 = __builtin_amdgcn_mfma_f32_16x16x32_bf16(A1, BB, a11, 0, 0, 0);
            a20 = __builtin_amdgcn_mfma_f32_16x16x32_bf16(A2, BA, a20, 0, 0, 0);
            a21 = __builtin_amdgcn_mfma_f32_16x16x32_bf16(A2, BB, a21, 0, 0, 0);
            a30 = __builtin_amdgcn_mfma_f32_16x16x32_bf16(A3, BA, a30, 0, 0, 0);
            a31 = __builtin_amdgcn_mfma_f32_16x16x32_bf16(A3, BB, a31, 0, 0, 0);

            t = tn;
            pc0 = pn0; pc1 = pn1; nc0 = nn0; nc1 = nn1;
            bAc = bAn; bBc = bBn;
        }
#undef SCM

        rsA += __shfl_xor(rsA, 16, 64);
        rsA += __shfl_xor(rsA, 32, 64);
        rsB += __shfl_xor(rsB, 16, 64);
        rsB += __shfl_xor(rsB, 32, 64);

        __syncthreads();
        float* rw = red + w * 2048 + l * 32;
        *(float4*)(rw + 0)  = *(float4*)&a00;
        *(float4*)(rw + 4)  = *(float4*)&a01;
        *(float4*)(rw + 8)  = *(float4*)&a10;
        *(float4*)(rw + 12) = *(float4*)&a11;
        *(float4*)(rw + 16) = *(float4*)&a20;
        *(float4*)(rw + 20) = *(float4*)&a21;
        *(float4*)(rw + 24) = *(float4*)&a30;
        *(float4*)(rw + 28) = *(float4*)&a31;
        if (l < 16) {
            redl[w * 32 + il]      = rsA;
            redl[w * 32 + 16 + il] = rsB;
        }
        __syncthreads();

        const int l2  = tid >> 2, q2 = tid & 3;
        const int il2 = l2 & 15, kg2 = l2 >> 4;
        #pragma unroll
        for (int h = 0; h < 2; ++h) {
            const int idx = l2 * 32 + q2 * 8 + h * 4;
            float4 s0 = *(float4*)(red + idx);
            float4 s1 = *(float4*)(red + 2048 + idx);
            float4 s2 = *(float4*)(red + 4096 + idx);
            float4 s3 = *(float4*)(red + 6144 + idx);
            float4 s;
            s.x = (s0.x + s1.x) + (s2.x + s3.x);
            s.y = (s0.y + s1.y) + (s2.y + s3.y);
            s.z = (s0.z + s1.z) + (s2.z + s3.z);
            s.w = (s0.w + s1.w) + (s2.w + s3.w);
            *(float4*)&Opart3[((size_t)split * NN + i0 + h * 16 + il2) * OUTF
                              + q2 * 16 + kg2 * 4] = s;
        }
        if (tid < 32)
            lpart3[(size_t)split * NN + i0 + tid] =
                (redl[tid] + redl[32 + tid]) + (redl[64 + tid] + redl[96 + tid]);
    }
}

extern "C" void kernel_launch(void* const* d_in, const int* in_sizes, int n_in,
                              void* d_out, int out_size, void* d_ws, size_t ws_size,
                              hipStream_t stream) {
    const float* x   = (const float*)d_in[0];
    const int*   adj = (const int*)d_in[1];
    const float* W   = (const float*)d_in[2];
    const float* a   = (const float*)d_in[3];
    float* out = (float*)d_out;

    char* ws = (char*)d_ws;
    unsigned short* Asw = (unsigned short*)ws;                        // 1 MB
    float* U     = (float*)(ws + (1 << 20));
    float* E2p   = (float*)(ws + (1 << 20) + 32768);
    float* E2n   = (float*)(ws + (1 << 20) + 65536);
    float* lpart = (float*)(ws + (1 << 20) + 98304);                  // 512 KB
    unsigned* mask = (unsigned*)(ws + (1 << 20) + 98304 + 524288);    // 8 MB
    float* Opart = (float*)(ws + (1 << 20) + 98304 + 524288 + (8 << 20)); // 32 MB

    // probe scratch (from 64 MB)
    char* pb = ws + ((size_t)64 << 20);
    unsigned short* Asw2 = (unsigned short*)pb;                       // 1 MB
    float* U2     = (float*)(pb + (1 << 20));
    float* E2p2   = (float*)(pb + (1 << 20) + 32768);
    float* E2n2   = (float*)(pb + (1 << 20) + 65536);
    unsigned* mask2 = (unsigned*)(pb + (2 << 20));                    // 8 MB
    float* Opart2 = (float*)(pb + (10 << 20));                        // 32 MB
    float* lpart2 = (float*)(pb + (42 << 20));                        // 512 KB
    float* Opart3 = (float*)(pb + (43 << 20));                        // 16 MB
    float* lpart3 = (float*)(pb + (59 << 20));                        // 256 KB

    // real pipeline (round-11 best)
    k01_fused<<<GEMM_BLOCKS + NN, 256, 0, stream>>>(x, adj, W, a, Asw,
                                                    U, E2p, E2n, mask);
    k2_attn<<<1024, 256, 0, stream>>>(mask, Asw, U, E2p, E2n, Opart, lpart);
    k3_combine<<<512, 256, 0, stream>>>(Opart, lpart, out);

    // probes (scratch only)
    probe_maskpack<<<8192, 256, 0, stream>>>(adj, mask2);
    probe_gemm<<<512, 256, 0, stream>>>(x, W, a, Asw2, U2, E2p2, E2n2);
    probe_k2attn<<<1024, 256, 0, stream>>>(mask, Asw, U, E2p, E2n, Opart2, lpart2);
    probe_k2fused<<<2048, 256, 0, stream>>>(adj, Asw, U, E2p, E2n, Opart3, lpart3);
}

// Round 16
// 111.149 us; speedup vs baseline: 12.8808x; 12.8808x over previous
//
#include <hip/hip_runtime.h>
#include <cstdint>
#include <cstddef>

#define NN 8192
#define INF 512
#define OUTF 64
#define ALPHA 0.2f
#define NSPLIT 16
#define JSPLIT (NN / NSPLIT)   // 512
#define NW32 (NN / 32)         // 256

typedef _Float16 half8 __attribute__((ext_vector_type(8)));
typedef float f32x4 __attribute__((ext_vector_type(4)));

static __device__ inline unsigned short f2h(float f) {
    _Float16 h = (_Float16)f;
    return __builtin_bit_cast(unsigned short, h);
}

// ---------------------------------------------------------------------------
// Kernel 01 (fused, INTERLEAVED): 8704 blocks = 512*17. Every 17th block
// (bid%17==16) is a GEMM block (g = bid/17); the rest are mask-pack blocks
// (row = bid - bid/17). GEMM blocks are spread through the dispatch so their
// latency-bound work (measured 17.3 us standalone) hides under the BW-bound
// adj stream (measured at the 45 us HBM floor) instead of preceding it.
// GEMM epilogue writes Asw in FP16 (MFMA-A-swizzled Wh), U=exp(.8 s1) f32,
// e2ph=exp(s2) fp16, e2nh=exp(.2 s2) fp16.
// ---------------------------------------------------------------------------
__global__ __launch_bounds__(256) void k01_fused(
    const float* __restrict__ x, const int* __restrict__ adj,
    const float* __restrict__ W, const float* __restrict__ a,
    unsigned short* __restrict__ Asw, float* __restrict__ U,
    unsigned short* __restrict__ e2ph, unsigned short* __restrict__ e2nh,
    unsigned* __restrict__ mask)
{
    __shared__ int ldsbuf[8192];   // 32 KB (mask path only)
    const int tid = threadIdx.x;
    const int bid = blockIdx.x;
    const int g   = bid / 17;

    if (bid % 17 != 16) {
        // ---------------- mask path: one adj row ----------------
        const int row = bid - g;           // 0..8191 bijective
        const int* arow = adj + (size_t)row * NN;

        #pragma unroll
        for (int k = 0; k < 8; ++k) {
            const int i = k * 1024 + tid * 4;
            int4 v = *(const int4*)(arow + i);
            const int p = i ^ (((i >> 7) & 7) << 2);
            *(int4*)&ldsbuf[p] = v;
        }
        __syncthreads();

        unsigned m = 0;
        #pragma unroll
        for (int k = 0; k < 8; ++k) {
            const int i2 = tid * 32 + k * 4;
            const int p2 = i2 ^ (((i2 >> 7) & 7) << 2);
            int4 v = *(const int4*)&ldsbuf[p2];
            m |= (v.x != 0 ? 1u : 0u) << (4 * k);
            m |= (v.y != 0 ? 1u : 0u) << (4 * k + 1);
            m |= (v.z != 0 ? 1u : 0u) << (4 * k + 2);
            m |= (v.w != 0 ? 1u : 0u) << (4 * k + 3);
        }
        mask[(size_t)row * NW32 + tid] = m;
        return;
    }

    // ---------------- GEMM path: 16 rows of Wh per gemm-block g ----------
    const int i0 = g * 16;
    const int w  = __builtin_amdgcn_readfirstlane(tid >> 6);
    const int c  = tid & 63;
    const float* xr = x + (size_t)(i0 + 4 * w) * INF;
    const float* Wc = W + c;
    float acc[4] = {0.f, 0.f, 0.f, 0.f};

    #pragma unroll 4
    for (int kk = 0; kk < 128; ++kk) {
        const float4 x0 = *(const float4*)(xr + 0 * INF + kk * 4);
        const float4 x1 = *(const float4*)(xr + 1 * INF + kk * 4);
        const float4 x2 = *(const float4*)(xr + 2 * INF + kk * 4);
        const float4 x3 = *(const float4*)(xr + 3 * INF + kk * 4);
        const float w0 = Wc[(kk * 4 + 0) * OUTF];
        const float w1 = Wc[(kk * 4 + 1) * OUTF];
        const float w2 = Wc[(kk * 4 + 2) * OUTF];
        const float w3 = Wc[(kk * 4 + 3) * OUTF];
        acc[0] = fmaf(x0.x, w0, fmaf(x0.y, w1, fmaf(x0.z, w2, fmaf(x0.w, w3, acc[0]))));
        acc[1] = fmaf(x1.x, w0, fmaf(x1.y, w1, fmaf(x1.z, w2, fmaf(x1.w, w3, acc[1]))));
        acc[2] = fmaf(x2.x, w0, fmaf(x2.y, w1, fmaf(x2.z, w2, fmaf(x2.w, w3, acc[2]))));
        acc[3] = fmaf(x3.x, w0, fmaf(x3.y, w1, fmaf(x3.z, w2, fmaf(x3.w, w3, acc[3]))));
    }

    const float a1c = a[c];
    const float a2c = a[64 + c];
    #pragma unroll
    for (int q = 0; q < 4; ++q) {
        float v1 = acc[q] * a1c;
        float v2 = acc[q] * a2c;
        #pragma unroll
        for (int m = 32; m; m >>= 1) {
            v1 += __shfl_xor(v1, m, 64);
            v2 += __shfl_xor(v2, m, 64);
        }
        if (c == 0) {
            const int i = i0 + 4 * w + q;
            U[i]    = __expf((1.0f - ALPHA) * v1);   // exp(0.8 s1), f32
            e2ph[i] = f2h(__expf(v2));               // exp(s2), fp16
            e2nh[i] = f2h(__expf(ALPHA * v2));       // exp(0.2 s2), fp16
        }
    }

    // A-fragment-swizzled store (same verified layout, now FP16)
    const int i   = i0 + 4 * w;
    const int jt  = i >> 5;
    const int sub = (i >> 3) & 3;
    const int e0  = i & 7;
    ushort4 pk;
    pk.x = f2h(acc[0]); pk.y = f2h(acc[1]);
    pk.z = f2h(acc[2]); pk.w = f2h(acc[3]);
    *(ushort4*)&Asw[((size_t)(c >> 4) * 256 + jt) * 512 + ((c & 15) + 16 * sub) * 8 + e0] = pk;
}

// ---------------------------------------------------------------------------
// Kernel 2: round-11 structure (task map, mask preload+shfl, in-step A loads,
// E2/mask one-step ping-pong) with the score core rewritten in PACKED FP16:
//   2 scores = v_pk_mul_f16 + v_pk_max_f16 + sign-extend AND-mask (v_bfi).
// B-fragment words produced directly (no cvt_pk); rowsums via ones-MFMA
// (denominator uses the exact same rounded P as the numerator).
// ---------------------------------------------------------------------------
__global__ __launch_bounds__(256, 4) void k2_attn(
    const unsigned* __restrict__ mask, const unsigned short* __restrict__ Asw,
    const float* __restrict__ Ug, const unsigned short* __restrict__ e2ph,
    const unsigned short* __restrict__ e2nh,
    float* __restrict__ Opart, float* __restrict__ lpart)
{
    const int l    = threadIdx.x & 63;
    const int task = blockIdx.x * 4 + (threadIdx.x >> 6);

    const int it    = task >> 4;
    const int split = task & 15;
    const int i0    = it * 32;
    const int jbase = split * JSPLIT;
    const int jb32  = jbase >> 5;

    const int il  = l & 15;
    const int kg  = l >> 4;
    const int kg8 = kg * 8;

    // ua/ub as packed half2 (x2 identical halves)
    const unsigned uaw = f2h(Ug[i0 + il]);
    const unsigned ubw = f2h(Ug[i0 + 16 + il]);
    const unsigned ua2 = uaw * 0x00010001u;
    const unsigned ub2 = ubw * 0x00010001u;

    const unsigned* mbase = mask + (size_t)(i0 + il) * NW32 + jb32 + kg;
    unsigned mA[4], mB[4];
    #pragma unroll
    for (int ss = 0; ss < 4; ++ss) {
        mA[ss] = mbase[ss * 4];
        mB[ss] = mbase[(size_t)16 * NW32 + ss * 4];
    }

    f32x4 a00 = {0,0,0,0}, a01 = {0,0,0,0}, a10 = {0,0,0,0}, a11 = {0,0,0,0};
    f32x4 a20 = {0,0,0,0}, a21 = {0,0,0,0}, a30 = {0,0,0,0}, a31 = {0,0,0,0};
    f32x4 sA  = {0,0,0,0}, sB  = {0,0,0,0};

    half8 ONESH;
    #pragma unroll
    for (int e = 0; e < 8; ++e) ONESH[e] = (_Float16)1.0f;

    // E2/mask ping-pong (fp16: one uint4 = 8 values)
    uint4 epc = *(const uint4*)(e2ph + jbase + kg8);
    uint4 enc = *(const uint4*)(e2nh + jbase + kg8);
    unsigned bAc = (__shfl(mA[0], il, 64) >> kg8) & 0xffu;
    unsigned bBc = (__shfl(mB[0], il, 64) >> kg8) & 0xffu;

// 2 scores: pk_mul + pk_max + sign-extend masks (compiler fuses to bfi) + and
#define SPAIR(DST, U2, EPW, ENW, BITS, R) do {                                \
    unsigned mu_, mx_;                                                        \
    asm("v_pk_mul_f16 %0, %1, %2" : "=v"(mu_) : "v"(U2), "v"(EPW));           \
    asm("v_pk_max_f16 %0, %1, %2" : "=v"(mx_) : "v"(mu_), "v"(ENW));          \
    const int lo_ = (int)((BITS) << (31 - 2 * (R))) >> 31;                    \
    const int hi_ = (int)((BITS) << (30 - 2 * (R))) >> 31;                    \
    DST = mx_ & (((unsigned)hi_ & 0xFFFF0000u) | ((unsigned)lo_ & 0x0000FFFFu)); \
} while (0)

    #pragma unroll
    for (int t = 0; t < 16; ++t) {
        // A-fragments for THIS step (fp16; consumed after the score core)
        const unsigned short* Ac = Asw + (size_t)(jb32 + t) * 512 + l * 8;
        half8 A0c = *(const half8*)(Ac);
        half8 A1c = *(const half8*)(Ac + 131072);
        half8 A2c = *(const half8*)(Ac + 262144);
        half8 A3c = *(const half8*)(Ac + 393216);

        // prefetch E2/mask for step t+1
        const int tn = (t < 15) ? t + 1 : t;
        uint4 epn = *(const uint4*)(e2ph + jbase + tn * 32 + kg8);
        uint4 enn = *(const uint4*)(e2nh + jbase + tn * 32 + kg8);
        const int ssn = tn >> 2, ksn = tn & 3;
        unsigned bAn = (__shfl(mA[ssn], il + 16 * ksn, 64) >> kg8) & 0xffu;
        unsigned bBn = (__shfl(mB[ssn], il + 16 * ksn, 64) >> kg8) & 0xffu;

        // packed-fp16 score core: 16 scores in ~48 VALU
        uint4 wa, wb;
        SPAIR(wa.x, ua2, epc.x, enc.x, bAc, 0);
        SPAIR(wa.y, ua2, epc.y, enc.y, bAc, 1);
        SPAIR(wa.z, ua2, epc.z, enc.z, bAc, 2);
        SPAIR(wa.w, ua2, epc.w, enc.w, bAc, 3);
        SPAIR(wb.x, ub2, epc.x, enc.x, bBc, 0);
        SPAIR(wb.y, ub2, epc.y, enc.y, bBc, 1);
        SPAIR(wb.z, ub2, epc.z, enc.z, bBc, 2);
        SPAIR(wb.w, ub2, epc.w, enc.w, bBc, 3);
        const half8 BA = __builtin_bit_cast(half8, wa);
        const half8 BB = __builtin_bit_cast(half8, wb);

        // rowsums on the matrix pipe (same rounded P as numerator)
        sA = __builtin_amdgcn_mfma_f32_16x16x32_f16(ONESH, BA, sA, 0, 0, 0);
        sB = __builtin_amdgcn_mfma_f32_16x16x32_f16(ONESH, BB, sB, 0, 0, 0);

        a00 = __builtin_amdgcn_mfma_f32_16x16x32_f16(A0c, BA, a00, 0, 0, 0);
        a01 = __builtin_amdgcn_mfma_f32_16x16x32_f16(A0c, BB, a01, 0, 0, 0);
        a10 = __builtin_amdgcn_mfma_f32_16x16x32_f16(A1c, BA, a10, 0, 0, 0);
        a11 = __builtin_amdgcn_mfma_f32_16x16x32_f16(A1c, BB, a11, 0, 0, 0);
        a20 = __builtin_amdgcn_mfma_f32_16x16x32_f16(A2c, BA, a20, 0, 0, 0);
        a21 = __builtin_amdgcn_mfma_f32_16x16x32_f16(A2c, BB, a21, 0, 0, 0);
        a30 = __builtin_amdgcn_mfma_f32_16x16x32_f16(A3c, BA, a30, 0, 0, 0);
        a31 = __builtin_amdgcn_mfma_f32_16x16x32_f16(A3c, BB, a31, 0, 0, 0);

        epc = epn; enc = enn;
        bAc = bAn; bBc = bBn;
    }
#undef SPAIR

    // lpart: lane l<16 (kg=0) reg0 holds the full split row-sum
    if (l < 16) {
        lpart[(size_t)split * NN + i0 + il]      = sA[0];
        lpart[(size_t)split * NN + i0 + 16 + il] = sB[0];
    }

    const int nn4 = kg * 4;
    float* OA = Opart + ((size_t)split * NN + i0 + il) * OUTF + nn4;
    float* OB = OA + (size_t)16 * OUTF;
    *(float4*)(OA)      = *(float4*)&a00;
    *(float4*)(OA + 16) = *(float4*)&a10;
    *(float4*)(OA + 32) = *(float4*)&a20;
    *(float4*)(OA + 48) = *(float4*)&a30;
    *(float4*)(OB)      = *(float4*)&a01;
    *(float4*)(OB + 16) = *(float4*)&a11;
    *(float4*)(OB + 32) = *(float4*)&a21;
    *(float4*)(OB + 48) = *(float4*)&a31;
}

// ---------------------------------------------------------------------------
// Kernel 3: combine the 16 j-split partials and normalize.
// ---------------------------------------------------------------------------
__global__ __launch_bounds__(256) void k3_combine(
    const float* __restrict__ Opart, const float* __restrict__ lpart,
    float* __restrict__ out)
{
    const int f4 = blockIdx.x * 256 + threadIdx.x;
    const int i  = f4 >> 4;

    float4 r = {0.f, 0.f, 0.f, 0.f};
    float  lsum = 0.f;
    #pragma unroll
    for (int s = 0; s < NSPLIT; ++s) {
        float4 o = *(const float4*)&Opart[(size_t)s * NN * OUTF + (size_t)f4 * 4];
        r.x += o.x; r.y += o.y; r.z += o.z; r.w += o.w;
        lsum += lpart[(size_t)s * NN + i];
    }
    float inv = 1.0f / lsum;
    r.x *= inv; r.y *= inv; r.z *= inv; r.w *= inv;
    *(float4*)&out[(size_t)f4 * 4] = r;
}

extern "C" void kernel_launch(void* const* d_in, const int* in_sizes, int n_in,
                              void* d_out, int out_size, void* d_ws, size_t ws_size,
                              hipStream_t stream) {
    const float* x   = (const float*)d_in[0];
    const int*   adj = (const int*)d_in[1];
    const float* W   = (const float*)d_in[2];
    const float* a   = (const float*)d_in[3];
    float* out = (float*)d_out;

    char* ws = (char*)d_ws;
    unsigned short* Asw = (unsigned short*)ws;                        // 1 MB
    float* U     = (float*)(ws + (1 << 20));                          // 32 KB
    unsigned short* e2ph = (unsigned short*)(ws + (1 << 20) + 32768); // 16 KB
    unsigned short* e2nh = (unsigned short*)(ws + (1 << 20) + 49152); // 16 KB
    float* lpart = (float*)(ws + (1 << 20) + 65536);                  // 512 KB
    unsigned* mask = (unsigned*)(ws + (1 << 20) + 65536 + 524288);    // 8 MB
    float* Opart = (float*)(ws + (1 << 20) + 65536 + 524288 + (8 << 20)); // 32 MB

    k01_fused<<<512 * 17, 256, 0, stream>>>(x, adj, W, a, Asw,
                                            U, e2ph, e2nh, mask);
    k2_attn<<<1024, 256, 0, stream>>>(mask, Asw, U, e2ph, e2nh, Opart, lpart);
    k3_combine<<<512, 256, 0, stream>>>(Opart, lpart, out);
}

// Round 17
// 93.261 us; speedup vs baseline: 15.3515x; 1.1918x over previous
//
#include <hip/hip_runtime.h>
#include <cstdint>
#include <cstddef>

#define NN 8192
#define INF 512
#define OUTF 64
#define ALPHA 0.2f
#define NSPLIT 16
#define JSPLIT (NN / NSPLIT)   // 512
#define NW32 (NN / 32)         // 256
#define GEMM_BLOCKS 512

typedef _Float16 half8 __attribute__((ext_vector_type(8)));
typedef float f32x4 __attribute__((ext_vector_type(4)));

static __device__ inline unsigned short f2h(float f) {
    _Float16 h = (_Float16)f;
    return __builtin_bit_cast(unsigned short, h);
}

// ---------------------------------------------------------------------------
// Kernel 01 (fused, GEMM-FIRST — round-11 proven layout): blocks 0..511 =
// GEMM (all start at t=0, finish ~17us, hidden under the 45us mask stream);
// blocks 512..8703 = adj->bitmask pack. Epilogue emits FP16 Asw/E2 vectors
// (U stays f32): U=exp(.8 s1), e2ph=exp(s2), e2nh=exp(.2 s2).
// ---------------------------------------------------------------------------
__global__ __launch_bounds__(256) void k01_fused(
    const float* __restrict__ x, const int* __restrict__ adj,
    const float* __restrict__ W, const float* __restrict__ a,
    unsigned short* __restrict__ Asw, float* __restrict__ U,
    unsigned short* __restrict__ e2ph, unsigned short* __restrict__ e2nh,
    unsigned* __restrict__ mask)
{
    __shared__ int ldsbuf[8192];   // 32 KB (mask path only)
    const int tid = threadIdx.x;

    if (blockIdx.x >= GEMM_BLOCKS) {
        // ---------------- mask path: one adj row ----------------
        const int row = blockIdx.x - GEMM_BLOCKS;
        const int* arow = adj + (size_t)row * NN;

        #pragma unroll
        for (int k = 0; k < 8; ++k) {
            const int i = k * 1024 + tid * 4;
            int4 v = *(const int4*)(arow + i);
            const int p = i ^ (((i >> 7) & 7) << 2);
            *(int4*)&ldsbuf[p] = v;
        }
        __syncthreads();

        unsigned m = 0;
        #pragma unroll
        for (int k = 0; k < 8; ++k) {
            const int i2 = tid * 32 + k * 4;
            const int p2 = i2 ^ (((i2 >> 7) & 7) << 2);
            int4 v = *(const int4*)&ldsbuf[p2];
            m |= (v.x != 0 ? 1u : 0u) << (4 * k);
            m |= (v.y != 0 ? 1u : 0u) << (4 * k + 1);
            m |= (v.z != 0 ? 1u : 0u) << (4 * k + 2);
            m |= (v.w != 0 ? 1u : 0u) << (4 * k + 3);
        }
        mask[(size_t)row * NW32 + tid] = m;
        return;
    }

    // ---------------- GEMM path: 16 rows of Wh per block ----------------
    const int i0 = blockIdx.x * 16;
    const int w  = __builtin_amdgcn_readfirstlane(tid >> 6);
    const int c  = tid & 63;
    const float* xr = x + (size_t)(i0 + 4 * w) * INF;
    const float* Wc = W + c;
    float acc[4] = {0.f, 0.f, 0.f, 0.f};

    #pragma unroll 4
    for (int kk = 0; kk < 128; ++kk) {
        const float4 x0 = *(const float4*)(xr + 0 * INF + kk * 4);
        const float4 x1 = *(const float4*)(xr + 1 * INF + kk * 4);
        const float4 x2 = *(const float4*)(xr + 2 * INF + kk * 4);
        const float4 x3 = *(const float4*)(xr + 3 * INF + kk * 4);
        const float w0 = Wc[(kk * 4 + 0) * OUTF];
        const float w1 = Wc[(kk * 4 + 1) * OUTF];
        const float w2 = Wc[(kk * 4 + 2) * OUTF];
        const float w3 = Wc[(kk * 4 + 3) * OUTF];
        acc[0] = fmaf(x0.x, w0, fmaf(x0.y, w1, fmaf(x0.z, w2, fmaf(x0.w, w3, acc[0]))));
        acc[1] = fmaf(x1.x, w0, fmaf(x1.y, w1, fmaf(x1.z, w2, fmaf(x1.w, w3, acc[1]))));
        acc[2] = fmaf(x2.x, w0, fmaf(x2.y, w1, fmaf(x2.z, w2, fmaf(x2.w, w3, acc[2]))));
        acc[3] = fmaf(x3.x, w0, fmaf(x3.y, w1, fmaf(x3.z, w2, fmaf(x3.w, w3, acc[3]))));
    }

    const float a1c = a[c];
    const float a2c = a[64 + c];
    #pragma unroll
    for (int q = 0; q < 4; ++q) {
        float v1 = acc[q] * a1c;
        float v2 = acc[q] * a2c;
        #pragma unroll
        for (int m = 32; m; m >>= 1) {
            v1 += __shfl_xor(v1, m, 64);
            v2 += __shfl_xor(v2, m, 64);
        }
        if (c == 0) {
            const int i = i0 + 4 * w + q;
            U[i]    = __expf((1.0f - ALPHA) * v1);   // exp(0.8 s1), f32
            e2ph[i] = f2h(__expf(v2));               // exp(s2), fp16
            e2nh[i] = f2h(__expf(ALPHA * v2));       // exp(0.2 s2), fp16
        }
    }

    // A-fragment-swizzled store (verified layout, FP16)
    const int i   = i0 + 4 * w;
    const int jt  = i >> 5;
    const int sub = (i >> 3) & 3;
    const int e0  = i & 7;
    ushort4 pk;
    pk.x = f2h(acc[0]); pk.y = f2h(acc[1]);
    pk.z = f2h(acc[2]); pk.w = f2h(acc[3]);
    *(ushort4*)&Asw[((size_t)(c >> 4) * 256 + jt) * 512 + ((c & 15) + 16 * sub) * 8 + e0] = pk;
}

// ---------------------------------------------------------------------------
// Kernel 2: round-11 structure with the PACKED-FP16 score core (the single
// change under test this round — verified correct in round 16):
//   2 scores = v_pk_mul_f16 + v_pk_max_f16 + sign-extend AND-mask.
// B-fragment words produced directly; rowsums via ones-MFMA (denominator
// uses the exact same rounded P as the numerator).
// ---------------------------------------------------------------------------
__global__ __launch_bounds__(256, 4) void k2_attn(
    const unsigned* __restrict__ mask, const unsigned short* __restrict__ Asw,
    const float* __restrict__ Ug, const unsigned short* __restrict__ e2ph,
    const unsigned short* __restrict__ e2nh,
    float* __restrict__ Opart, float* __restrict__ lpart)
{
    const int l    = threadIdx.x & 63;
    const int task = blockIdx.x * 4 + (threadIdx.x >> 6);

    const int it    = task >> 4;
    const int split = task & 15;
    const int i0    = it * 32;
    const int jbase = split * JSPLIT;
    const int jb32  = jbase >> 5;

    const int il  = l & 15;
    const int kg  = l >> 4;
    const int kg8 = kg * 8;

    const unsigned uaw = f2h(Ug[i0 + il]);
    const unsigned ubw = f2h(Ug[i0 + 16 + il]);
    const unsigned ua2 = uaw * 0x00010001u;
    const unsigned ub2 = ubw * 0x00010001u;

    const unsigned* mbase = mask + (size_t)(i0 + il) * NW32 + jb32 + kg;
    unsigned mA[4], mB[4];
    #pragma unroll
    for (int ss = 0; ss < 4; ++ss) {
        mA[ss] = mbase[ss * 4];
        mB[ss] = mbase[(size_t)16 * NW32 + ss * 4];
    }

    f32x4 a00 = {0,0,0,0}, a01 = {0,0,0,0}, a10 = {0,0,0,0}, a11 = {0,0,0,0};
    f32x4 a20 = {0,0,0,0}, a21 = {0,0,0,0}, a30 = {0,0,0,0}, a31 = {0,0,0,0};
    f32x4 sA  = {0,0,0,0}, sB  = {0,0,0,0};

    half8 ONESH;
    #pragma unroll
    for (int e = 0; e < 8; ++e) ONESH[e] = (_Float16)1.0f;

    uint4 epc = *(const uint4*)(e2ph + jbase + kg8);
    uint4 enc = *(const uint4*)(e2nh + jbase + kg8);
    unsigned bAc = (__shfl(mA[0], il, 64) >> kg8) & 0xffu;
    unsigned bBc = (__shfl(mB[0], il, 64) >> kg8) & 0xffu;

#define SPAIR(DST, U2, EPW, ENW, BITS, R) do {                                \
    unsigned mu_, mx_;                                                        \
    asm("v_pk_mul_f16 %0, %1, %2" : "=v"(mu_) : "v"(U2), "v"(EPW));           \
    asm("v_pk_max_f16 %0, %1, %2" : "=v"(mx_) : "v"(mu_), "v"(ENW));          \
    const int lo_ = (int)((BITS) << (31 - 2 * (R))) >> 31;                    \
    const int hi_ = (int)((BITS) << (30 - 2 * (R))) >> 31;                    \
    DST = mx_ & (((unsigned)hi_ & 0xFFFF0000u) | ((unsigned)lo_ & 0x0000FFFFu)); \
} while (0)

    #pragma unroll
    for (int t = 0; t < 16; ++t) {
        const unsigned short* Ac = Asw + (size_t)(jb32 + t) * 512 + l * 8;
        half8 A0c = *(const half8*)(Ac);
        half8 A1c = *(const half8*)(Ac + 131072);
        half8 A2c = *(const half8*)(Ac + 262144);
        half8 A3c = *(const half8*)(Ac + 393216);

        const int tn = (t < 15) ? t + 1 : t;
        uint4 epn = *(const uint4*)(e2ph + jbase + tn * 32 + kg8);
        uint4 enn = *(const uint4*)(e2nh + jbase + tn * 32 + kg8);
        const int ssn = tn >> 2, ksn = tn & 3;
        unsigned bAn = (__shfl(mA[ssn], il + 16 * ksn, 64) >> kg8) & 0xffu;
        unsigned bBn = (__shfl(mB[ssn], il + 16 * ksn, 64) >> kg8) & 0xffu;

        uint4 wa, wb;
        SPAIR(wa.x, ua2, epc.x, enc.x, bAc, 0);
        SPAIR(wa.y, ua2, epc.y, enc.y, bAc, 1);
        SPAIR(wa.z, ua2, epc.z, enc.z, bAc, 2);
        SPAIR(wa.w, ua2, epc.w, enc.w, bAc, 3);
        SPAIR(wb.x, ub2, epc.x, enc.x, bBc, 0);
        SPAIR(wb.y, ub2, epc.y, enc.y, bBc, 1);
        SPAIR(wb.z, ub2, epc.z, enc.z, bBc, 2);
        SPAIR(wb.w, ub2, epc.w, enc.w, bBc, 3);
        const half8 BA = __builtin_bit_cast(half8, wa);
        const half8 BB = __builtin_bit_cast(half8, wb);

        sA = __builtin_amdgcn_mfma_f32_16x16x32_f16(ONESH, BA, sA, 0, 0, 0);
        sB = __builtin_amdgcn_mfma_f32_16x16x32_f16(ONESH, BB, sB, 0, 0, 0);

        a00 = __builtin_amdgcn_mfma_f32_16x16x32_f16(A0c, BA, a00, 0, 0, 0);
        a01 = __builtin_amdgcn_mfma_f32_16x16x32_f16(A0c, BB, a01, 0, 0, 0);
        a10 = __builtin_amdgcn_mfma_f32_16x16x32_f16(A1c, BA, a10, 0, 0, 0);
        a11 = __builtin_amdgcn_mfma_f32_16x16x32_f16(A1c, BB, a11, 0, 0, 0);
        a20 = __builtin_amdgcn_mfma_f32_16x16x32_f16(A2c, BA, a20, 0, 0, 0);
        a21 = __builtin_amdgcn_mfma_f32_16x16x32_f16(A2c, BB, a21, 0, 0, 0);
        a30 = __builtin_amdgcn_mfma_f32_16x16x32_f16(A3c, BA, a30, 0, 0, 0);
        a31 = __builtin_amdgcn_mfma_f32_16x16x32_f16(A3c, BB, a31, 0, 0, 0);

        epc = epn; enc = enn;
        bAc = bAn; bBc = bBn;
    }
#undef SPAIR

    if (l < 16) {
        lpart[(size_t)split * NN + i0 + il]      = sA[0];
        lpart[(size_t)split * NN + i0 + 16 + il] = sB[0];
    }

    const int nn4 = kg * 4;
    float* OA = Opart + ((size_t)split * NN + i0 + il) * OUTF + nn4;
    float* OB = OA + (size_t)16 * OUTF;
    *(float4*)(OA)      = *(float4*)&a00;
    *(float4*)(OA + 16) = *(float4*)&a10;
    *(float4*)(OA + 32) = *(float4*)&a20;
    *(float4*)(OA + 48) = *(float4*)&a30;
    *(float4*)(OB)      = *(float4*)&a01;
    *(float4*)(OB + 16) = *(float4*)&a11;
    *(float4*)(OB + 32) = *(float4*)&a21;
    *(float4*)(OB + 48) = *(float4*)&a31;
}

// ---------------------------------------------------------------------------
// Kernel 3: combine the 16 j-split partials and normalize.
// ---------------------------------------------------------------------------
__global__ __launch_bounds__(256) void k3_combine(
    const float* __restrict__ Opart, const float* __restrict__ lpart,
    float* __restrict__ out)
{
    const int f4 = blockIdx.x * 256 + threadIdx.x;
    const int i  = f4 >> 4;

    float4 r = {0.f, 0.f, 0.f, 0.f};
    float  lsum = 0.f;
    #pragma unroll
    for (int s = 0; s < NSPLIT; ++s) {
        float4 o = *(const float4*)&Opart[(size_t)s * NN * OUTF + (size_t)f4 * 4];
        r.x += o.x; r.y += o.y; r.z += o.z; r.w += o.w;
        lsum += lpart[(size_t)s * NN + i];
    }
    float inv = 1.0f / lsum;
    r.x *= inv; r.y *= inv; r.z *= inv; r.w *= inv;
    *(float4*)&out[(size_t)f4 * 4] = r;
}

extern "C" void kernel_launch(void* const* d_in, const int* in_sizes, int n_in,
                              void* d_out, int out_size, void* d_ws, size_t ws_size,
                              hipStream_t stream) {
    const float* x   = (const float*)d_in[0];
    const int*   adj = (const int*)d_in[1];
    const float* W   = (const float*)d_in[2];
    const float* a   = (const float*)d_in[3];
    float* out = (float*)d_out;

    char* ws = (char*)d_ws;
    unsigned short* Asw = (unsigned short*)ws;                        // 1 MB
    float* U     = (float*)(ws + (1 << 20));                          // 32 KB
    unsigned short* e2ph = (unsigned short*)(ws + (1 << 20) + 32768); // 16 KB
    unsigned short* e2nh = (unsigned short*)(ws + (1 << 20) + 49152); // 16 KB
    float* lpart = (float*)(ws + (1 << 20) + 65536);                  // 512 KB
    unsigned* mask = (unsigned*)(ws + (1 << 20) + 65536 + 524288);    // 8 MB
    float* Opart = (float*)(ws + (1 << 20) + 65536 + 524288 + (8 << 20)); // 32 MB

    k01_fused<<<GEMM_BLOCKS + NN, 256, 0, stream>>>(x, adj, W, a, Asw,
                                                    U, e2ph, e2nh, mask);
    k2_attn<<<1024, 256, 0, stream>>>(mask, Asw, U, e2ph, e2nh, Opart, lpart);
    k3_combine<<<512, 256, 0, stream>>>(Opart, lpart, out);
}

// Round 18
// 77.285 us; speedup vs baseline: 18.5248x; 1.2067x over previous
//
#include <hip/hip_runtime.h>
#include <cstdint>
#include <cstddef>

#define NN 8192
#define INF 512
#define OUTF 64
#define ALPHA 0.2f
#define JSPLIT 512             // j-chunk per wave (16 waves cover 8192)
#define NW32 (NN / 32)         // 256
#define GEMM_BLOCKS 512
#define RSTRIDE 36             // LDS acc row stride (pad: b128-write bank floor)

typedef _Float16 half8 __attribute__((ext_vector_type(8)));
typedef float f32x4 __attribute__((ext_vector_type(4)));

static __device__ inline unsigned short f2h(float f) {
    _Float16 h = (_Float16)f;
    return __builtin_bit_cast(unsigned short, h);
}

// ---------------------------------------------------------------------------
// Kernel 01 (fused, GEMM-FIRST — proven layout): blocks 0..511 = GEMM (start
// at t=0, ~17us, hidden under the 45us mask stream); blocks 512..8703 =
// adj->bitmask pack. Epilogue emits FP16 Asw/E2 (U stays f32):
// U=exp(.8 s1), e2ph=exp(s2), e2nh=exp(.2 s2).
// ---------------------------------------------------------------------------
__global__ __launch_bounds__(256) void k01_fused(
    const float* __restrict__ x, const int* __restrict__ adj,
    const float* __restrict__ W, const float* __restrict__ a,
    unsigned short* __restrict__ Asw, float* __restrict__ U,
    unsigned short* __restrict__ e2ph, unsigned short* __restrict__ e2nh,
    unsigned* __restrict__ mask)
{
    __shared__ int ldsbuf[8192];   // 32 KB (mask path only)
    const int tid = threadIdx.x;

    if (blockIdx.x >= GEMM_BLOCKS) {
        // ---------------- mask path: one adj row ----------------
        const int row = blockIdx.x - GEMM_BLOCKS;
        const int* arow = adj + (size_t)row * NN;

        #pragma unroll
        for (int k = 0; k < 8; ++k) {
            const int i = k * 1024 + tid * 4;
            int4 v = *(const int4*)(arow + i);
            const int p = i ^ (((i >> 7) & 7) << 2);
            *(int4*)&ldsbuf[p] = v;
        }
        __syncthreads();

        unsigned m = 0;
        #pragma unroll
        for (int k = 0; k < 8; ++k) {
            const int i2 = tid * 32 + k * 4;
            const int p2 = i2 ^ (((i2 >> 7) & 7) << 2);
            int4 v = *(const int4*)&ldsbuf[p2];
            m |= (v.x != 0 ? 1u : 0u) << (4 * k);
            m |= (v.y != 0 ? 1u : 0u) << (4 * k + 1);
            m |= (v.z != 0 ? 1u : 0u) << (4 * k + 2);
            m |= (v.w != 0 ? 1u : 0u) << (4 * k + 3);
        }
        mask[(size_t)row * NW32 + tid] = m;
        return;
    }

    // ---------------- GEMM path: 16 rows of Wh per block ----------------
    const int i0 = blockIdx.x * 16;
    const int w  = __builtin_amdgcn_readfirstlane(tid >> 6);
    const int c  = tid & 63;
    const float* xr = x + (size_t)(i0 + 4 * w) * INF;
    const float* Wc = W + c;
    float acc[4] = {0.f, 0.f, 0.f, 0.f};

    #pragma unroll 4
    for (int kk = 0; kk < 128; ++kk) {
        const float4 x0 = *(const float4*)(xr + 0 * INF + kk * 4);
        const float4 x1 = *(const float4*)(xr + 1 * INF + kk * 4);
        const float4 x2 = *(const float4*)(xr + 2 * INF + kk * 4);
        const float4 x3 = *(const float4*)(xr + 3 * INF + kk * 4);
        const float w0 = Wc[(kk * 4 + 0) * OUTF];
        const float w1 = Wc[(kk * 4 + 1) * OUTF];
        const float w2 = Wc[(kk * 4 + 2) * OUTF];
        const float w3 = Wc[(kk * 4 + 3) * OUTF];
        acc[0] = fmaf(x0.x, w0, fmaf(x0.y, w1, fmaf(x0.z, w2, fmaf(x0.w, w3, acc[0]))));
        acc[1] = fmaf(x1.x, w0, fmaf(x1.y, w1, fmaf(x1.z, w2, fmaf(x1.w, w3, acc[1]))));
        acc[2] = fmaf(x2.x, w0, fmaf(x2.y, w1, fmaf(x2.z, w2, fmaf(x2.w, w3, acc[2]))));
        acc[3] = fmaf(x3.x, w0, fmaf(x3.y, w1, fmaf(x3.z, w2, fmaf(x3.w, w3, acc[3]))));
    }

    const float a1c = a[c];
    const float a2c = a[64 + c];
    #pragma unroll
    for (int q = 0; q < 4; ++q) {
        float v1 = acc[q] * a1c;
        float v2 = acc[q] * a2c;
        #pragma unroll
        for (int m = 32; m; m >>= 1) {
            v1 += __shfl_xor(v1, m, 64);
            v2 += __shfl_xor(v2, m, 64);
        }
        if (c == 0) {
            const int i = i0 + 4 * w + q;
            U[i]    = __expf((1.0f - ALPHA) * v1);   // exp(0.8 s1), f32
            e2ph[i] = f2h(__expf(v2));               // exp(s2), fp16
            e2nh[i] = f2h(__expf(ALPHA * v2));       // exp(0.2 s2), fp16
        }
    }

    const int i   = i0 + 4 * w;
    const int jt  = i >> 5;
    const int sub = (i >> 3) & 3;
    const int e0  = i & 7;
    ushort4 pk;
    pk.x = f2h(acc[0]); pk.y = f2h(acc[1]);
    pk.z = f2h(acc[2]); pk.w = f2h(acc[3]);
    *(ushort4*)&Asw[((size_t)(c >> 4) * 256 + jt) * 512 + ((c & 15) + 16 * sub) * 8 + e0] = pk;
}

// ---------------------------------------------------------------------------
// Kernel 2 (MERGED k2+k3): block = 1024 threads = 16 waves; block owns a full
// 32-row i-tile; wave w owns j-chunk [w*512, w*512+512). Inner loop is the
// verified round-17 packed-fp16 body, byte-identical. Epilogue: all 16 waves
// reduce numerator+denominator in LDS (stride-36 pad) and write the FINAL
// normalized output directly — Opart/lpart/k3 eliminated.
// ---------------------------------------------------------------------------
__global__ __launch_bounds__(1024, 4) void k2_final(
    const unsigned* __restrict__ mask, const unsigned short* __restrict__ Asw,
    const float* __restrict__ Ug, const unsigned short* __restrict__ e2ph,
    const unsigned short* __restrict__ e2nh,
    float* __restrict__ out)
{
    __shared__ float red[16 * 64 * RSTRIDE];   // 144 KB acc partials
    __shared__ float redl[16 * 32];            // 2 KB rowsum partials

    const int tid   = threadIdx.x;
    const int l     = tid & 63;
    const int w     = tid >> 6;                // 0..15 = j-chunk
    const int i0    = blockIdx.x * 32;
    const int jbase = w * JSPLIT;
    const int jb32  = jbase >> 5;

    const int il  = l & 15;
    const int kg  = l >> 4;
    const int kg8 = kg * 8;

    const unsigned uaw = f2h(Ug[i0 + il]);
    const unsigned ubw = f2h(Ug[i0 + 16 + il]);
    const unsigned ua2 = uaw * 0x00010001u;
    const unsigned ub2 = ubw * 0x00010001u;

    const unsigned* mbase = mask + (size_t)(i0 + il) * NW32 + jb32 + kg;
    unsigned mA[4], mB[4];
    #pragma unroll
    for (int ss = 0; ss < 4; ++ss) {
        mA[ss] = mbase[ss * 4];
        mB[ss] = mbase[(size_t)16 * NW32 + ss * 4];
    }

    f32x4 a00 = {0,0,0,0}, a01 = {0,0,0,0}, a10 = {0,0,0,0}, a11 = {0,0,0,0};
    f32x4 a20 = {0,0,0,0}, a21 = {0,0,0,0}, a30 = {0,0,0,0}, a31 = {0,0,0,0};
    f32x4 sA  = {0,0,0,0}, sB  = {0,0,0,0};

    half8 ONESH;
    #pragma unroll
    for (int e = 0; e < 8; ++e) ONESH[e] = (_Float16)1.0f;

    uint4 epc = *(const uint4*)(e2ph + jbase + kg8);
    uint4 enc = *(const uint4*)(e2nh + jbase + kg8);
    unsigned bAc = (__shfl(mA[0], il, 64) >> kg8) & 0xffu;
    unsigned bBc = (__shfl(mB[0], il, 64) >> kg8) & 0xffu;

#define SPAIR(DST, U2, EPW, ENW, BITS, R) do {                                \
    unsigned mu_, mx_;                                                        \
    asm("v_pk_mul_f16 %0, %1, %2" : "=v"(mu_) : "v"(U2), "v"(EPW));           \
    asm("v_pk_max_f16 %0, %1, %2" : "=v"(mx_) : "v"(mu_), "v"(ENW));          \
    const int lo_ = (int)((BITS) << (31 - 2 * (R))) >> 31;                    \
    const int hi_ = (int)((BITS) << (30 - 2 * (R))) >> 31;                    \
    DST = mx_ & (((unsigned)hi_ & 0xFFFF0000u) | ((unsigned)lo_ & 0x0000FFFFu)); \
} while (0)

    #pragma unroll
    for (int t = 0; t < 16; ++t) {
        const unsigned short* Ac = Asw + (size_t)(jb32 + t) * 512 + l * 8;
        half8 A0c = *(const half8*)(Ac);
        half8 A1c = *(const half8*)(Ac + 131072);
        half8 A2c = *(const half8*)(Ac + 262144);
        half8 A3c = *(const half8*)(Ac + 393216);

        const int tn = (t < 15) ? t + 1 : t;
        uint4 epn = *(const uint4*)(e2ph + jbase + tn * 32 + kg8);
        uint4 enn = *(const uint4*)(e2nh + jbase + tn * 32 + kg8);
        const int ssn = tn >> 2, ksn = tn & 3;
        unsigned bAn = (__shfl(mA[ssn], il + 16 * ksn, 64) >> kg8) & 0xffu;
        unsigned bBn = (__shfl(mB[ssn], il + 16 * ksn, 64) >> kg8) & 0xffu;

        uint4 wa, wb;
        SPAIR(wa.x, ua2, epc.x, enc.x, bAc, 0);
        SPAIR(wa.y, ua2, epc.y, enc.y, bAc, 1);
        SPAIR(wa.z, ua2, epc.z, enc.z, bAc, 2);
        SPAIR(wa.w, ua2, epc.w, enc.w, bAc, 3);
        SPAIR(wb.x, ub2, epc.x, enc.x, bBc, 0);
        SPAIR(wb.y, ub2, epc.y, enc.y, bBc, 1);
        SPAIR(wb.z, ub2, epc.z, enc.z, bBc, 2);
        SPAIR(wb.w, ub2, epc.w, enc.w, bBc, 3);
        const half8 BA = __builtin_bit_cast(half8, wa);
        const half8 BB = __builtin_bit_cast(half8, wb);

        sA = __builtin_amdgcn_mfma_f32_16x16x32_f16(ONESH, BA, sA, 0, 0, 0);
        sB = __builtin_amdgcn_mfma_f32_16x16x32_f16(ONESH, BB, sB, 0, 0, 0);

        a00 = __builtin_amdgcn_mfma_f32_16x16x32_f16(A0c, BA, a00, 0, 0, 0);
        a01 = __builtin_amdgcn_mfma_f32_16x16x32_f16(A0c, BB, a01, 0, 0, 0);
        a10 = __builtin_amdgcn_mfma_f32_16x16x32_f16(A1c, BA, a10, 0, 0, 0);
        a11 = __builtin_amdgcn_mfma_f32_16x16x32_f16(A1c, BB, a11, 0, 0, 0);
        a20 = __builtin_amdgcn_mfma_f32_16x16x32_f16(A2c, BA, a20, 0, 0, 0);
        a21 = __builtin_amdgcn_mfma_f32_16x16x32_f16(A2c, BB, a21, 0, 0, 0);
        a30 = __builtin_amdgcn_mfma_f32_16x16x32_f16(A3c, BA, a30, 0, 0, 0);
        a31 = __builtin_amdgcn_mfma_f32_16x16x32_f16(A3c, BB, a31, 0, 0, 0);

        epc = epn; enc = enn;
        bAc = bAn; bBc = bBn;
    }
#undef SPAIR

    // ---- merged epilogue: block-wide reduce over the 16 j-chunk waves ----
    float* rw = red + (size_t)(w * 64 + l) * RSTRIDE;
    *(float4*)(rw + 0)  = *(float4*)&a00;   // q0 h0
    *(float4*)(rw + 4)  = *(float4*)&a01;   // q0 h1
    *(float4*)(rw + 8)  = *(float4*)&a10;
    *(float4*)(rw + 12) = *(float4*)&a11;
    *(float4*)(rw + 16) = *(float4*)&a20;
    *(float4*)(rw + 20) = *(float4*)&a21;
    *(float4*)(rw + 24) = *(float4*)&a30;
    *(float4*)(rw + 28) = *(float4*)&a31;
    if (l < 16) {
        redl[w * 32 + il]      = sA[0];     // rowsum, row i0+il (this chunk)
        redl[w * 32 + 16 + il] = sB[0];     // rowsum, row i0+16+il
    }
    __syncthreads();

    // thread t -> output (row = t>>5, cols n0..n0+1), fully coalesced store
    const int row = tid >> 5;            // 0..31
    const int n0  = (tid & 31) * 2;      // 0,2,...,62
    const int h   = row >> 4;
    const int il2 = row & 15;

    float den = 0.f;
    #pragma unroll
    for (int w2 = 0; w2 < 16; ++w2) den += redl[w2 * 32 + row];
    const float inv = 1.0f / den;

    float o2[2];
    #pragma unroll
    for (int e = 0; e < 2; ++e) {
        const int n   = n0 + e;
        const int q   = n >> 4;
        const int kg2 = (n >> 2) & 3;
        const int r   = n & 3;
        float s = 0.f;
        #pragma unroll
        for (int w2 = 0; w2 < 16; ++w2)
            s += red[(size_t)(w2 * 64 + kg2 * 16 + il2) * RSTRIDE + q * 8 + h * 4 + r];
        o2[e] = s * inv;
    }
    *(float2*)&out[(size_t)(i0 + row) * OUTF + n0] = *(float2*)o2;
}

extern "C" void kernel_launch(void* const* d_in, const int* in_sizes, int n_in,
                              void* d_out, int out_size, void* d_ws, size_t ws_size,
                              hipStream_t stream) {
    const float* x   = (const float*)d_in[0];
    const int*   adj = (const int*)d_in[1];
    const float* W   = (const float*)d_in[2];
    const float* a   = (const float*)d_in[3];
    float* out = (float*)d_out;

    char* ws = (char*)d_ws;
    unsigned short* Asw = (unsigned short*)ws;                        // 1 MB
    float* U     = (float*)(ws + (1 << 20));                          // 32 KB
    unsigned short* e2ph = (unsigned short*)(ws + (1 << 20) + 32768); // 16 KB
    unsigned short* e2nh = (unsigned short*)(ws + (1 << 20) + 49152); // 16 KB
    unsigned* mask = (unsigned*)(ws + (1 << 20) + 65536);             // 8 MB

    k01_fused<<<GEMM_BLOCKS + NN, 256, 0, stream>>>(x, adj, W, a, Asw,
                                                    U, e2ph, e2nh, mask);
    k2_final<<<NN / 32, 1024, 0, stream>>>(mask, Asw, U, e2ph, e2nh, out);
}